// Round 4
// baseline (195.691 us; speedup 1.0000x reference)
//
#include <hip/hip_runtime.h>
#include <hip/hip_bf16.h>

// MultiHeadRelationAwareAttention on MI355X (gfx950), bf16 MFMA pipeline:
//   conv_all : fp32 -> bf16 copies of x, Wq, Wk, Wv, Wo
//   gemm_qkv : 128x128 tile, 8 waves. Q=(x Wq^T+bq)*0.125*log2e; K; V^T per head
//   attn_fwd : flash attention, kv-split x2 (grid 512 -> 2 blocks/CU);
//              S^T = mfma(K,Q) keeps P lane-local; unnormalized fp32 partials
//   combine  : merge the two kv-half partials with (m,l)
//   gemm_out : 64x128 tile, 8 waves, out = attn Wo^T + bo (fp32)

typedef float    f32x4  __attribute__((ext_vector_type(4)));
typedef __bf16   bf16x8 __attribute__((ext_vector_type(8)));
typedef unsigned short u16;
typedef u16      u16x8  __attribute__((ext_vector_type(8)));
typedef u16      u16x4  __attribute__((ext_vector_type(4)));

__device__ __forceinline__ u16 f2bf(float f){
  __hip_bfloat16 h = __float2bfloat16(f);
  return __builtin_bit_cast(u16, h);
}
__device__ __forceinline__ float exp2_fast(float x){
  float r; asm("v_exp_f32 %0, %1" : "=v"(r) : "v"(x)); return r;
}
__device__ __forceinline__ unsigned cvt_pk_bf16(float lo, float hi){  // D = [bf16(hi):bf16(lo)]
  unsigned r; asm("v_cvt_pk_bf16_f32 %0, %1, %2" : "=v"(r) : "v"(lo), "v"(hi)); return r;
}
__device__ __forceinline__ f32x4 mfma16(u16x8 a, u16x8 b, f32x4 c){
  return __builtin_amdgcn_mfma_f32_16x16x32_bf16(
      __builtin_bit_cast(bf16x8, a), __builtin_bit_cast(bf16x8, b), c, 0, 0, 0);
}
__device__ __forceinline__ f32x4 vmax4(f32x4 a, f32x4 b){
  f32x4 r;
#pragma unroll
  for (int i = 0; i < 4; ++i) r[i] = fmaxf(a[i], b[i]);
  return r;
}
// XOR swizzle for 128B-row-stride LDS tiles (byte bits 4..6 ^= bits 7..9).
__device__ __forceinline__ int swz7(int b){ return b ^ (((b >> 7) & 7) << 4); }

// ---------------------------------------------------------------- conv_all
__global__ __launch_bounds__(256) void conv_all(
    const float* __restrict__ x,
    const float* __restrict__ wq, const float* __restrict__ wk,
    const float* __restrict__ wv, const float* __restrict__ wo,
    u16* __restrict__ xb, u16* __restrict__ wqb, u16* __restrict__ wkb,
    u16* __restrict__ wvb, u16* __restrict__ wob)
{
  int i = blockIdx.x * 256 + threadIdx.x;   // float4 index, total 786432
  const float* s; u16* d; int j;
  if      (i < 524288) { s = x;  d = xb;  j = i; }
  else if (i < 589824) { s = wq; d = wqb; j = i - 524288; }
  else if (i < 655360) { s = wk; d = wkb; j = i - 589824; }
  else if (i < 720896) { s = wv; d = wvb; j = i - 655360; }
  else                 { s = wo; d = wob; j = i - 720896; }
  float4 v = ((const float4*)s)[j];
  u16x4 o; o[0] = f2bf(v.x); o[1] = f2bf(v.y); o[2] = f2bf(v.z); o[3] = f2bf(v.w);
  ((u16x4*)d)[j] = o;
}

// ------------------------------------------------------- gemm core 128x128
// 512 threads = 8 waves (4m x 2n), wave tile 32x64, BK=64, dbuf LDS,
// issue-early/write-late prefetch, one barrier per kt.
__device__ __forceinline__ void gemm_core_128(
    const u16* __restrict__ A, const u16* __restrict__ W,
    int bm, int bn, u16* As, u16* Bs, f32x4 (&acc)[2][4], int tid)
{
  const int lane = tid & 63, wid = tid >> 6;
  const int wm = wid >> 1, wn = wid & 1;
  const int c = lane & 15, g = lane >> 4;
  const int rr = tid >> 3, co = tid & 7;           // 64 rows / stage-iter
  const u16* Ab = A + (bm * 128 + rr) * 512 + co * 8;
  const u16* Wb = W + (bn * 128 + rr) * 512 + co * 8;
#pragma unroll
  for (int it = 0; it < 2; ++it) {
    *(uint4*)((char*)As + swz7((it * 64 + rr) * 128 + co * 16)) =
        *(const uint4*)(Ab + it * 64 * 512);
    *(uint4*)((char*)Bs + swz7((it * 64 + rr) * 128 + co * 16)) =
        *(const uint4*)(Wb + it * 64 * 512);
  }
  __syncthreads();
  for (int kt = 0; kt < 8; ++kt) {
    const int cur = kt & 1;
    uint4 pa[2], pw[2];
    if (kt < 7) {
#pragma unroll
      for (int it = 0; it < 2; ++it) {
        pa[it] = *(const uint4*)(Ab + it * 64 * 512 + (kt + 1) * 64);
        pw[it] = *(const uint4*)(Wb + it * 64 * 512 + (kt + 1) * 64);
      }
    }
    const char* Ar = (const char*)As + cur * 16384;
    const char* Wr = (const char*)Bs + cur * 16384;
#pragma unroll
    for (int kk = 0; kk < 2; ++kk) {
      u16x8 af[2], bfr[4];
#pragma unroll
      for (int mf = 0; mf < 2; ++mf) {
        int row = wm * 32 + mf * 16 + c;
        af[mf] = *(const u16x8*)(Ar + swz7(row * 128 + kk * 64 + g * 16));
      }
#pragma unroll
      for (int nf = 0; nf < 4; ++nf) {
        int row = wn * 64 + nf * 16 + c;
        bfr[nf] = *(const u16x8*)(Wr + swz7(row * 128 + kk * 64 + g * 16));
      }
#pragma unroll
      for (int mf = 0; mf < 2; ++mf)
#pragma unroll
        for (int nf = 0; nf < 4; ++nf)
          acc[mf][nf] = mfma16(af[mf], bfr[nf], acc[mf][nf]);
    }
    if (kt < 7) {
      char* Ad = (char*)As + (cur ^ 1) * 16384;
      char* Wd = (char*)Bs + (cur ^ 1) * 16384;
#pragma unroll
      for (int it = 0; it < 2; ++it) {
        *(uint4*)(Ad + swz7((it * 64 + rr) * 128 + co * 16)) = pa[it];
        *(uint4*)(Wd + swz7((it * 64 + rr) * 128 + co * 16)) = pw[it];
      }
    }
    __syncthreads();
  }
}

// ------------------------------------------------------------- gemm_qkv
__global__ __launch_bounds__(512) void gemm_qkv(
    const u16* __restrict__ xb,
    const u16* __restrict__ wqb, const u16* __restrict__ wkb, const u16* __restrict__ wvb,
    const float* __restrict__ bq, const float* __restrict__ bk, const float* __restrict__ bv,
    u16* __restrict__ Qw, u16* __restrict__ Kw, u16* __restrict__ Vt)
{
  __shared__ __align__(16) u16 As[2 * 128 * 64];   // 32KB
  __shared__ __align__(16) u16 Bs[2 * 128 * 64];   // 32KB
  const int tid = threadIdx.x, z = blockIdx.z;
  const int bm = blockIdx.x, bn = blockIdx.y;
  const u16*   W    = (z == 0) ? wqb : (z == 1) ? wkb : wvb;
  const float* bias = (z == 0) ? bq : (z == 1) ? bk : bv;
  const f32x4 Z4 = {0.f, 0.f, 0.f, 0.f};
  f32x4 acc[2][4];
#pragma unroll
  for (int a = 0; a < 2; ++a)
#pragma unroll
    for (int b = 0; b < 4; ++b) acc[a][b] = Z4;
  gemm_core_128(xb, W, bm, bn, As, Bs, acc, tid);
  const int lane = tid & 63, wid = tid >> 6;
  const int wm = wid >> 1, wn = wid & 1, c = lane & 15, g = lane >> 4;
  const float sc = (z == 0) ? 0.125f * 1.44269504088896f : 1.0f;  // 1/sqrt(dk)*log2e
#pragma unroll
  for (int mf = 0; mf < 2; ++mf)
#pragma unroll
    for (int nf = 0; nf < 4; ++nf) {
      int o  = bn * 128 + wn * 64 + nf * 16 + c;
      int h  = o >> 6, d = o & 63;
      int ib = bm * 128 + wm * 32 + mf * 16 + 4 * g;   // 4 consecutive rows
      float bb = bias[o];
      f32x4 v = acc[mf][nf];
      if (z == 2) {           // V -> transposed per head [8][64][4096]
        u16x4 pk;
#pragma unroll
        for (int r = 0; r < 4; ++r) pk[r] = f2bf(v[r] + bb);
        *(u16x4*)&Vt[h * 262144 + d * 4096 + ib] = pk;
      } else {                // Q/K -> head-major [8][4096][64]
        u16* out = (z == 0) ? Qw : Kw;
#pragma unroll
        for (int r = 0; r < 4; ++r)
          out[h * 262144 + (ib + r) * 64 + d] = f2bf((v[r] + bb) * sc);
      }
    }
}

// ------------------------------------------------------------- attn_fwd
// Grid (256, 2): x&7 = head (XCD-local K/V), x>>3 = q-block, y = kv-half.
// 4 waves x 32q, BQ=128, BKV=64, 32 tiles per block; dbuf K/V, one barrier
// per tile; outputs UNNORMALIZED fp32 O^T partial + (m,l) per q.
__global__ __launch_bounds__(256) void attn_fwd(
    const u16* __restrict__ Qw, const u16* __restrict__ Kw, const u16* __restrict__ Vt,
    float* __restrict__ Opart, float* __restrict__ ml)
{
  __shared__ __align__(16) u16 Qs[128 * 64];      // 16KB
  __shared__ __align__(16) u16 Ks[2 * 64 * 64];   // 16KB dbuf
  __shared__ __align__(16) u16 Vs[2 * 64 * 64];   // 16KB dbuf (V^T tiles)
  const int tid = threadIdx.x, lane = tid & 63, w = tid >> 6;
  const int c = lane & 15, g = lane >> 4;
  const int h = blockIdx.x & 7, qb = blockIdx.x >> 3, q0 = qb * 128;
  const int kvh = blockIdx.y, t0 = kvh * 32;
  const u16* gQ = Qw + h * 262144;
  const u16* gK = Kw + h * 262144;
  const u16* gV = Vt + h * 262144;

  // stage Q [128][64] (pre-scaled by 0.125*log2e)
#pragma unroll
  for (int it = 0; it < 4; ++it) {
    int beta = it * 256 + tid, r = beta >> 3, co = beta & 7;
    uint4 v = *(const uint4*)(gQ + (q0 + r) * 64 + co * 8);
    *(uint4*)((char*)Qs + swz7(r * 128 + co * 16)) = v;
  }
  // stage K,V tile t0 into buffer 0
#pragma unroll
  for (int it = 0; it < 2; ++it) {
    int beta = it * 256 + tid, r = beta >> 3, co = beta & 7;
    uint4 vk = *(const uint4*)(gK + (t0 * 64 + r) * 64 + co * 8);
    uint4 vv = *(const uint4*)(gV + r * 4096 + t0 * 64 + co * 8);
    int by = swz7(r * 128 + co * 16);
    *(uint4*)((char*)Ks + by) = vk;
    *(uint4*)((char*)Vs + by) = vv;
  }
  __syncthreads();

  // hoist Q B-frags (per wave: q = w*32 + nf*16 + c)
  u16x8 qf[2][2];
#pragma unroll
  for (int nf = 0; nf < 2; ++nf)
#pragma unroll
    for (int kk = 0; kk < 2; ++kk) {
      int q = w * 32 + nf * 16 + c;
      qf[nf][kk] = *(const u16x8*)((const char*)Qs + swz7(q * 128 + kk * 64 + g * 16));
    }

  const f32x4 Z4 = {0.f, 0.f, 0.f, 0.f};
  f32x4 o_[4][2];                      // O^T: rows d (4 frags), cols q (2 nf)
#pragma unroll
  for (int mfd = 0; mfd < 4; ++mfd) { o_[mfd][0] = Z4; o_[mfd][1] = Z4; }
  float m_run[2] = {-1e30f, -1e30f};
  float l_run[2] = {0.f, 0.f};

  for (int t = t0; t < t0 + 32; ++t) {
    const int cur = t & 1;
    const char* kb = (const char*)Ks + cur * 8192;
    const char* vb = (const char*)Vs + cur * 8192;
    uint4 rgK[2], rgV[2];
    if (t < t0 + 31) {                 // issue next-tile loads early (T14)
      const int kv1 = (t + 1) * 64;
#pragma unroll
      for (int it = 0; it < 2; ++it) {
        int beta = it * 256 + tid, r = beta >> 3, co = beta & 7;
        rgK[it] = *(const uint4*)(gK + (kv1 + r) * 64 + co * 8);
        rgV[it] = *(const uint4*)(gV + r * 4096 + kv1 + co * 8);
      }
    }

    // S^T = mfma(K, Q): C rows = kv (16mf + 4g + r), cols = q (c)
    f32x4 s[4][2];
#pragma unroll
    for (int mf = 0; mf < 4; ++mf) { s[mf][0] = Z4; s[mf][1] = Z4; }
    __builtin_amdgcn_s_setprio(1);     // T5: favor MFMA-issuing wave
#pragma unroll
    for (int kk = 0; kk < 2; ++kk)
#pragma unroll
      for (int mf = 0; mf < 4; ++mf) {
        u16x8 kf = *(const u16x8*)(kb + swz7((c + 16 * mf) * 128 + kk * 64 + g * 16));
        s[mf][0] = mfma16(kf, qf[0][kk], s[mf][0]);
        s[mf][1] = mfma16(kf, qf[1][kk], s[mf][1]);
      }
    __builtin_amdgcn_s_setprio(0);

    // online softmax per q column, log2 domain; balanced trees
#pragma unroll
    for (int nf = 0; nf < 2; ++nf) {
      f32x4 mm = vmax4(vmax4(s[0][nf], s[1][nf]), vmax4(s[2][nf], s[3][nf]));
      float mt = fmaxf(fmaxf(mm[0], mm[1]), fmaxf(mm[2], mm[3]));
      mt = fmaxf(mt, __shfl_xor(mt, 16));
      mt = fmaxf(mt, __shfl_xor(mt, 32));
      if (!__all(mt - m_run[nf] <= 8.0f)) {   // T13 defer-rescale (2^8 bound)
        float mn = fmaxf(m_run[nf], mt);
        float al = exp2_fast(m_run[nf] - mn);
        m_run[nf] = mn;
        l_run[nf] *= al;
#pragma unroll
        for (int mfd = 0; mfd < 4; ++mfd) o_[mfd][nf] *= al;
      }
      float mn = m_run[nf];
#pragma unroll
      for (int mf = 0; mf < 4; ++mf)
#pragma unroll
        for (int r = 0; r < 4; ++r) s[mf][nf][r] = exp2_fast(s[mf][nf][r] - mn);
      f32x4 ss = (s[0][nf] + s[1][nf]) + (s[2][nf] + s[3][nf]);
      float lt = (ss[0] + ss[1]) + (ss[2] + ss[3]);
      lt += __shfl_xor(lt, 16);
      lt += __shfl_xor(lt, 32);
      l_run[nf] += lt;
    }

    // PV: O^T += V^T * P^T.  P slot k-map equals C-frag row map (lane-local);
    // V^T A-frags read with the SAME slot map -> consistent contraction.
#pragma unroll
    for (int kap = 0; kap < 2; ++kap) {
      u16x8 pb[2];
#pragma unroll
      for (int nf = 0; nf < 2; ++nf) {
        uint4 wd;
        wd.x = cvt_pk_bf16(s[2 * kap][nf][0],     s[2 * kap][nf][1]);
        wd.y = cvt_pk_bf16(s[2 * kap][nf][2],     s[2 * kap][nf][3]);
        wd.z = cvt_pk_bf16(s[2 * kap + 1][nf][0], s[2 * kap + 1][nf][1]);
        wd.w = cvt_pk_bf16(s[2 * kap + 1][nf][2], s[2 * kap + 1][nf][3]);
        pb[nf] = __builtin_bit_cast(u16x8, wd);
      }
      __builtin_amdgcn_s_setprio(1);
#pragma unroll
      for (int mfd = 0; mfd < 4; ++mfd) {
        int e = (c + 16 * mfd) * 128 + kap * 64 + g * 8;   // bytes in V^T tile
        u16x4 lo = *(const u16x4*)(vb + swz7(e));
        u16x4 hi = *(const u16x4*)(vb + swz7(e + 32));
        u16x8 vf = __builtin_shufflevector(lo, hi, 0, 1, 2, 3, 4, 5, 6, 7);
        o_[mfd][0] = mfma16(vf, pb[0], o_[mfd][0]);
        o_[mfd][1] = mfma16(vf, pb[1], o_[mfd][1]);
      }
      __builtin_amdgcn_s_setprio(0);
    }

    if (t < t0 + 31) {                 // write-late into the other buffer
      char* kd = (char*)Ks + (cur ^ 1) * 8192;
      char* vd = (char*)Vs + (cur ^ 1) * 8192;
#pragma unroll
      for (int it = 0; it < 2; ++it) {
        int beta = it * 256 + tid, r = beta >> 3, co = beta & 7;
        int by = swz7(r * 128 + co * 16);
        *(uint4*)(kd + by) = rgK[it];
        *(uint4*)(vd + by) = rgV[it];
      }
    }
    __syncthreads();
  }

  // epilogue: unnormalized fp32 partials + (m,l)
#pragma unroll
  for (int nf = 0; nf < 2; ++nf) {
    int q = q0 + w * 32 + nf * 16 + c;
    float* Ob = Opart + (((size_t)kvh * 8 + h) * 4096 + q) * 64;
#pragma unroll
    for (int mfd = 0; mfd < 4; ++mfd)
      *(f32x4*)(Ob + mfd * 16 + 4 * g) = o_[mfd][nf];
    if (g == 0) {
      float* mp = ml + ((kvh * 8 + h) * 4096 + q) * 2;
      mp[0] = m_run[nf];
      mp[1] = l_run[nf];
    }
  }
}

// ------------------------------------------------------------- combine
__global__ __launch_bounds__(256) void combine(
    const float* __restrict__ Opart, const float* __restrict__ ml,
    u16* __restrict__ ab)
{
  int idx = blockIdx.x * 256 + threadIdx.x;   // (h,q): 32768
  int h = idx >> 12, q = idx & 4095;
  const float* m0p = ml + (h * 4096 + q) * 2;
  const float* m1p = ml + ((8 + h) * 4096 + q) * 2;
  float m0 = m0p[0], l0 = m0p[1], m1 = m1p[0], l1 = m1p[1];
  float m  = fmaxf(m0, m1);
  float w0 = exp2_fast(m0 - m), w1 = exp2_fast(m1 - m);
  float inv = 1.0f / (l0 * w0 + l1 * w1);
  float a0 = w0 * inv, a1 = w1 * inv;
  const float* O0 = Opart + ((size_t)h * 4096 + q) * 64;
  const float* O1 = Opart + (((size_t)8 + h) * 4096 + q) * 64;
  u16* dst = ab + (size_t)q * 512 + h * 64;
#pragma unroll
  for (int d0 = 0; d0 < 16; ++d0) {
    float4 x0 = *(const float4*)(O0 + d0 * 4);
    float4 x1 = *(const float4*)(O1 + d0 * 4);
    u16x4 pk;
    pk[0] = f2bf(x0.x * a0 + x1.x * a1);
    pk[1] = f2bf(x0.y * a0 + x1.y * a1);
    pk[2] = f2bf(x0.z * a0 + x1.z * a1);
    pk[3] = f2bf(x0.w * a0 + x1.w * a1);
    *(u16x4*)(dst + d0 * 4) = pk;
  }
}

// ------------------------------------------------------------- gemm_out
// 64x128 tile, 512 threads = 8 waves (4m x 2n), wave tile 16x64.
__global__ __launch_bounds__(512) void gemm_out(
    const u16* __restrict__ ab, const u16* __restrict__ wob,
    const float* __restrict__ bo, float* __restrict__ out)
{
  __shared__ __align__(16) u16 As[2 * 64 * 64];    // 16KB
  __shared__ __align__(16) u16 Bs[2 * 128 * 64];   // 32KB
  const int tid = threadIdx.x, bm = blockIdx.x, bn = blockIdx.y;
  const int lane = tid & 63, wid = tid >> 6;
  const int wm = wid >> 1, wn = wid & 1;
  const int c = lane & 15, g = lane >> 4;
  const int rr = tid >> 3, co = tid & 7;
  const f32x4 Z4 = {0.f, 0.f, 0.f, 0.f};
  f32x4 acc[4];
#pragma unroll
  for (int b = 0; b < 4; ++b) acc[b] = Z4;
  const u16* Ab = ab  + (bm * 64 + rr) * 512 + co * 8;     // rr 0..63
  const u16* Wb = wob + (bn * 128 + rr) * 512 + co * 8;
  *(uint4*)((char*)As + swz7(rr * 128 + co * 16)) = *(const uint4*)(Ab);
#pragma unroll
  for (int it = 0; it < 2; ++it)
    *(uint4*)((char*)Bs + swz7((it * 64 + rr) * 128 + co * 16)) =
        *(const uint4*)(Wb + it * 64 * 512);
  __syncthreads();
  for (int kt = 0; kt < 8; ++kt) {
    const int cur = kt & 1;
    uint4 pa, pw[2];
    if (kt < 7) {
      pa = *(const uint4*)(Ab + (kt + 1) * 64);
#pragma unroll
      for (int it = 0; it < 2; ++it)
        pw[it] = *(const uint4*)(Wb + it * 64 * 512 + (kt + 1) * 64);
    }
    const char* Ar = (const char*)As + cur * 8192;
    const char* Wr = (const char*)Bs + cur * 16384;
#pragma unroll
    for (int kk = 0; kk < 2; ++kk) {
      u16x8 af, bfr[4];
      af = *(const u16x8*)(Ar + swz7((wm * 16 + c) * 128 + kk * 64 + g * 16));
#pragma unroll
      for (int nf = 0; nf < 4; ++nf) {
        int row = wn * 64 + nf * 16 + c;
        bfr[nf] = *(const u16x8*)(Wr + swz7(row * 128 + kk * 64 + g * 16));
      }
#pragma unroll
      for (int nf = 0; nf < 4; ++nf)
        acc[nf] = mfma16(af, bfr[nf], acc[nf]);
    }
    if (kt < 7) {
      char* Ad = (char*)As + (cur ^ 1) * 8192;
      char* Wd = (char*)Bs + (cur ^ 1) * 16384;
      *(uint4*)(Ad + swz7(rr * 128 + co * 16)) = pa;
#pragma unroll
      for (int it = 0; it < 2; ++it)
        *(uint4*)(Wd + swz7((it * 64 + rr) * 128 + co * 16)) = pw[it];
    }
    __syncthreads();
  }
#pragma unroll
  for (int nf = 0; nf < 4; ++nf) {
    int o  = bn * 128 + wn * 64 + nf * 16 + c;
    int ib = bm * 64 + wm * 16 + 4 * g;
    float bb = bo[o];
#pragma unroll
    for (int r = 0; r < 4; ++r) out[(ib + r) * 512 + o] = acc[nf][r] + bb;
  }
}

// ------------------------------------------------------------- launch
extern "C" void kernel_launch(void* const* d_in, const int* in_sizes, int n_in,
                              void* d_out, int out_size, void* d_ws, size_t ws_size,
                              hipStream_t stream) {
  (void)in_sizes; (void)n_in; (void)out_size; (void)ws_size;
  const float* x  = (const float*)d_in[0];
  const float* Wq = (const float*)d_in[1];
  const float* bq = (const float*)d_in[2];
  const float* Wk = (const float*)d_in[3];
  const float* bk = (const float*)d_in[4];
  const float* Wv = (const float*)d_in[5];
  const float* bv = (const float*)d_in[6];
  const float* Wo = (const float*)d_in[7];
  const float* bo = (const float*)d_in[8];
  char* ws = (char*)d_ws;
  u16*   xb  = (u16*)(ws + 0);           // x bf16            4 MB
  u16*   wqb = (u16*)(ws + 4194304);     // weights bf16  4x 0.5 MB
  u16*   wkb = (u16*)(ws + 4718592);
  u16*   wvb = (u16*)(ws + 5242880);
  u16*   wob = (u16*)(ws + 5767168);
  u16*   Qw  = (u16*)(ws + 6291456);     // Q  [8][4096][64]  4 MB (scaled)
  u16*   Kw  = (u16*)(ws + 10485760);    // K  [8][4096][64]  4 MB
  u16*   Vt  = (u16*)(ws + 14680064);    // V^T [8][64][4096] 4 MB
  u16*   ab  = (u16*)(ws + 18874368);    // attn bf16 [4096][512] 4 MB
  float* Op  = (float*)(ws + 23068672);  // O partial [2][8][4096][64] f32 16 MB
  float* ml  = (float*)(ws + 39845888);  // (m,l) [2][8][4096][2] f32 0.5 MB

  conv_all<<<3072, 256, 0, stream>>>(x, Wq, Wk, Wv, Wo, xb, wqb, wkb, wvb, wob);
  gemm_qkv<<<dim3(32, 4, 3), 512, 0, stream>>>(xb, wqb, wkb, wvb, bq, bk, bv, Qw, Kw, Vt);
  attn_fwd<<<dim3(256, 2), 256, 0, stream>>>(Qw, Kw, Vt, Op, ml);
  combine<<<128, 256, 0, stream>>>(Op, ml, ab);
  gemm_out<<<dim3(64, 4), 512, 0, stream>>>(ab, wob, bo, (float*)d_out);
}

// Round 6
// 162.682 us; speedup vs baseline: 1.2029x; 1.2029x over previous
//
#include <hip/hip_runtime.h>
#include <hip/hip_bf16.h>

// MultiHeadRelationAwareAttention on MI355X (gfx950), bf16 MFMA pipeline:
//   conv_all : fp32 -> bf16 copies of x, Wq, Wk, Wv, Wo
//   gemm_qkv : 128x128 tile, 8 waves. Q=(x Wq^T+bq)*0.125*log2e; K; V^T per head
//   attn_fwd : flash attention, single-pass, quad-buffered K/V (1 barrier per
//              2 tiles), lazy-max shuffle-free softmax, S^T = mfma(K,Q) keeps
//              P lane-local (consistent-k-permutation trick)
//   gemm_out : 64x128 tile, 8 waves, out = attn Wo^T + bo (fp32)

typedef float    f32x4  __attribute__((ext_vector_type(4)));
typedef __bf16   bf16x8 __attribute__((ext_vector_type(8)));
typedef unsigned short u16;
typedef u16      u16x8  __attribute__((ext_vector_type(8)));
typedef u16      u16x4  __attribute__((ext_vector_type(4)));

__device__ __forceinline__ u16 f2bf(float f){
  __hip_bfloat16 h = __float2bfloat16(f);
  return __builtin_bit_cast(u16, h);
}
__device__ __forceinline__ float exp2_fast(float x){
  float r; asm("v_exp_f32 %0, %1" : "=v"(r) : "v"(x)); return r;
}
__device__ __forceinline__ unsigned cvt_pk_bf16(float lo, float hi){  // D = [bf16(hi):bf16(lo)]
  unsigned r; asm("v_cvt_pk_bf16_f32 %0, %1, %2" : "=v"(r) : "v"(lo), "v"(hi)); return r;
}
__device__ __forceinline__ f32x4 mfma16(u16x8 a, u16x8 b, f32x4 c){
  return __builtin_amdgcn_mfma_f32_16x16x32_bf16(
      __builtin_bit_cast(bf16x8, a), __builtin_bit_cast(bf16x8, b), c, 0, 0, 0);
}
__device__ __forceinline__ f32x4 vmax4(f32x4 a, f32x4 b){
  f32x4 r;
#pragma unroll
  for (int i = 0; i < 4; ++i) r[i] = fmaxf(a[i], b[i]);
  return r;
}
// XOR swizzle for 128B-row-stride LDS tiles (byte bits 4..6 ^= bits 7..9).
__device__ __forceinline__ int swz7(int b){ return b ^ (((b >> 7) & 7) << 4); }

// ---------------------------------------------------------------- conv_all
__global__ __launch_bounds__(256) void conv_all(
    const float* __restrict__ x,
    const float* __restrict__ wq, const float* __restrict__ wk,
    const float* __restrict__ wv, const float* __restrict__ wo,
    u16* __restrict__ xb, u16* __restrict__ wqb, u16* __restrict__ wkb,
    u16* __restrict__ wvb, u16* __restrict__ wob)
{
  int i = blockIdx.x * 256 + threadIdx.x;   // float4 index, total 786432
  const float* s; u16* d; int j;
  if      (i < 524288) { s = x;  d = xb;  j = i; }
  else if (i < 589824) { s = wq; d = wqb; j = i - 524288; }
  else if (i < 655360) { s = wk; d = wkb; j = i - 589824; }
  else if (i < 720896) { s = wv; d = wvb; j = i - 655360; }
  else                 { s = wo; d = wob; j = i - 720896; }
  float4 v = ((const float4*)s)[j];
  u16x4 o; o[0] = f2bf(v.x); o[1] = f2bf(v.y); o[2] = f2bf(v.z); o[3] = f2bf(v.w);
  ((u16x4*)d)[j] = o;
}

// ------------------------------------------------------- gemm core 128x128
// 512 threads = 8 waves (4m x 2n), wave tile 32x64, BK=64, dbuf LDS,
// issue-early/write-late prefetch, one barrier per kt.
__device__ __forceinline__ void gemm_core_128(
    const u16* __restrict__ A, const u16* __restrict__ W,
    int bm, int bn, u16* As, u16* Bs, f32x4 (&acc)[2][4], int tid)
{
  const int lane = tid & 63, wid = tid >> 6;
  const int wm = wid >> 1, wn = wid & 1;
  const int c = lane & 15, g = lane >> 4;
  const int rr = tid >> 3, co = tid & 7;           // 64 rows / stage-iter
  const u16* Ab = A + (bm * 128 + rr) * 512 + co * 8;
  const u16* Wb = W + (bn * 128 + rr) * 512 + co * 8;
#pragma unroll
  for (int it = 0; it < 2; ++it) {
    *(uint4*)((char*)As + swz7((it * 64 + rr) * 128 + co * 16)) =
        *(const uint4*)(Ab + it * 64 * 512);
    *(uint4*)((char*)Bs + swz7((it * 64 + rr) * 128 + co * 16)) =
        *(const uint4*)(Wb + it * 64 * 512);
  }
  __syncthreads();
  for (int kt = 0; kt < 8; ++kt) {
    const int cur = kt & 1;
    uint4 pa[2], pw[2];
    if (kt < 7) {
#pragma unroll
      for (int it = 0; it < 2; ++it) {
        pa[it] = *(const uint4*)(Ab + it * 64 * 512 + (kt + 1) * 64);
        pw[it] = *(const uint4*)(Wb + it * 64 * 512 + (kt + 1) * 64);
      }
    }
    const char* Ar = (const char*)As + cur * 16384;
    const char* Wr = (const char*)Bs + cur * 16384;
#pragma unroll
    for (int kk = 0; kk < 2; ++kk) {
      u16x8 af[2], bfr[4];
#pragma unroll
      for (int mf = 0; mf < 2; ++mf) {
        int row = wm * 32 + mf * 16 + c;
        af[mf] = *(const u16x8*)(Ar + swz7(row * 128 + kk * 64 + g * 16));
      }
#pragma unroll
      for (int nf = 0; nf < 4; ++nf) {
        int row = wn * 64 + nf * 16 + c;
        bfr[nf] = *(const u16x8*)(Wr + swz7(row * 128 + kk * 64 + g * 16));
      }
#pragma unroll
      for (int mf = 0; mf < 2; ++mf)
#pragma unroll
        for (int nf = 0; nf < 4; ++nf)
          acc[mf][nf] = mfma16(af[mf], bfr[nf], acc[mf][nf]);
    }
    if (kt < 7) {
      char* Ad = (char*)As + (cur ^ 1) * 16384;
      char* Wd = (char*)Bs + (cur ^ 1) * 16384;
#pragma unroll
      for (int it = 0; it < 2; ++it) {
        *(uint4*)(Ad + swz7((it * 64 + rr) * 128 + co * 16)) = pa[it];
        *(uint4*)(Wd + swz7((it * 64 + rr) * 128 + co * 16)) = pw[it];
      }
    }
    __syncthreads();
  }
}

// ------------------------------------------------------------- gemm_qkv
__global__ __launch_bounds__(512) void gemm_qkv(
    const u16* __restrict__ xb,
    const u16* __restrict__ wqb, const u16* __restrict__ wkb, const u16* __restrict__ wvb,
    const float* __restrict__ bq, const float* __restrict__ bk, const float* __restrict__ bv,
    u16* __restrict__ Qw, u16* __restrict__ Kw, u16* __restrict__ Vt)
{
  __shared__ __align__(16) u16 As[2 * 128 * 64];   // 32KB
  __shared__ __align__(16) u16 Bs[2 * 128 * 64];   // 32KB
  const int tid = threadIdx.x, z = blockIdx.z;
  const int bm = blockIdx.x, bn = blockIdx.y;
  const u16*   W    = (z == 0) ? wqb : (z == 1) ? wkb : wvb;
  const float* bias = (z == 0) ? bq : (z == 1) ? bk : bv;
  const f32x4 Z4 = {0.f, 0.f, 0.f, 0.f};
  f32x4 acc[2][4];
#pragma unroll
  for (int a = 0; a < 2; ++a)
#pragma unroll
    for (int b = 0; b < 4; ++b) acc[a][b] = Z4;
  gemm_core_128(xb, W, bm, bn, As, Bs, acc, tid);
  const int lane = tid & 63, wid = tid >> 6;
  const int wm = wid >> 1, wn = wid & 1, c = lane & 15, g = lane >> 4;
  const float sc = (z == 0) ? 0.125f * 1.44269504088896f : 1.0f;  // 1/sqrt(dk)*log2e
#pragma unroll
  for (int mf = 0; mf < 2; ++mf)
#pragma unroll
    for (int nf = 0; nf < 4; ++nf) {
      int o  = bn * 128 + wn * 64 + nf * 16 + c;
      int h  = o >> 6, d = o & 63;
      int ib = bm * 128 + wm * 32 + mf * 16 + 4 * g;   // 4 consecutive rows
      float bb = bias[o];
      f32x4 v = acc[mf][nf];
      if (z == 2) {           // V -> transposed per head [8][64][4096]
        u16x4 pk;
#pragma unroll
        for (int r = 0; r < 4; ++r) pk[r] = f2bf(v[r] + bb);
        *(u16x4*)&Vt[h * 262144 + d * 4096 + ib] = pk;
      } else {                // Q/K -> head-major [8][4096][64]
        u16* out = (z == 0) ? Qw : Kw;
#pragma unroll
        for (int r = 0; r < 4; ++r)
          out[h * 262144 + (ib + r) * 64 + d] = f2bf((v[r] + bb) * sc);
      }
    }
}

// ------------------------------------------------------------- attn_fwd
// Grid 256: x&7 = head (XCD-local K/V in L2), x>>3 = q-block. 4 waves x 32q,
// BQ=128, BKV=64, 64 tiles. Quad-buffered K/V: compute 2 tiles + prefetch 2
// tiles per iteration, ONE barrier per pair. Lazy-max shuffle-free softmax
// (log2 domain, Q pre-scaled by 0.125*log2e); per-lane l partials.
__global__ __launch_bounds__(256) void attn_fwd(
    const u16* __restrict__ Qw, const u16* __restrict__ Kw, const u16* __restrict__ Vt,
    u16* __restrict__ ab)
{
  __shared__ __align__(16) u16 Qs[128 * 64];      // 16KB
  __shared__ __align__(16) u16 Ks[4 * 64 * 64];   // 32KB quad
  __shared__ __align__(16) u16 Vs[4 * 64 * 64];   // 32KB quad (V^T tiles)
  const int tid = threadIdx.x, lane = tid & 63, w = tid >> 6;
  const int c = lane & 15, g = lane >> 4;
  const int h = blockIdx.x & 7, qb = blockIdx.x >> 3, q0 = qb * 128;
  const u16* gQ = Qw + h * 262144;
  const u16* gK = Kw + h * 262144;
  const u16* gV = Vt + h * 262144;
  const int rr = tid >> 3, co = tid & 7;           // staging coords (32 rows/iter)

  // stage Q [128][64] (pre-scaled by 0.125*log2e)
#pragma unroll
  for (int it = 0; it < 4; ++it) {
    int beta = it * 256 + tid, r = beta >> 3, cq = beta & 7;
    uint4 v = *(const uint4*)(gQ + (q0 + r) * 64 + cq * 8);
    *(uint4*)((char*)Qs + swz7(r * 128 + cq * 16)) = v;
  }
  // stage K,V tiles 0 and 1 into buffers 0,1
#pragma unroll
  for (int u = 0; u < 2; ++u)
#pragma unroll
    for (int it = 0; it < 2; ++it) {
      int r = it * 32 + rr;
      uint4 vk = *(const uint4*)(gK + (u * 64 + r) * 64 + co * 8);
      uint4 vv = *(const uint4*)(gV + r * 4096 + u * 64 + co * 8);
      int by = u * 8192 + swz7(r * 128 + co * 16);
      *(uint4*)((char*)Ks + by) = vk;
      *(uint4*)((char*)Vs + by) = vv;
    }
  __syncthreads();

  // hoist Q B-frags (per wave: q = w*32 + nf*16 + c)
  u16x8 qf[2][2];
#pragma unroll
  for (int nf = 0; nf < 2; ++nf)
#pragma unroll
    for (int kk = 0; kk < 2; ++kk) {
      int q = w * 32 + nf * 16 + c;
      qf[nf][kk] = *(const u16x8*)((const char*)Qs + swz7(q * 128 + kk * 64 + g * 16));
    }

  const f32x4 Z4 = {0.f, 0.f, 0.f, 0.f};
  f32x4 o_[4][2];                      // O^T: rows d (4 frags), cols q (2 nf)
#pragma unroll
  for (int mfd = 0; mfd < 4; ++mfd) { o_[mfd][0] = Z4; o_[mfd][1] = Z4; }
  float m_run[2] = {-1e30f, -1e30f};
  f32x4 l_acc[2] = {Z4, Z4};           // per-lane l partials (reduced at end)

  // one kv-tile: QK^T -> lazy-max softmax -> PV
  auto tile_step = [&](const char* kb, const char* vb) {
    // S^T = mfma(K, Q): C rows = kv (16mf + 4g + r), cols = q (c)
    f32x4 s[4][2];
#pragma unroll
    for (int mf = 0; mf < 4; ++mf) { s[mf][0] = Z4; s[mf][1] = Z4; }
#pragma unroll
    for (int kk = 0; kk < 2; ++kk)
#pragma unroll
      for (int mf = 0; mf < 4; ++mf) {
        u16x8 kf = *(const u16x8*)(kb + swz7((c + 16 * mf) * 128 + kk * 64 + g * 16));
        s[mf][0] = mfma16(kf, qf[0][kk], s[mf][0]);
        s[mf][1] = mfma16(kf, qf[1][kk], s[mf][1]);
      }

    // lazy-max online softmax (log2 domain): common path has NO cross-lane ops
#pragma unroll
    for (int nf = 0; nf < 2; ++nf) {
      f32x4 mm = vmax4(vmax4(s[0][nf], s[1][nf]), vmax4(s[2][nf], s[3][nf]));
      float mt = fmaxf(fmaxf(mm[0], mm[1]), fmaxf(mm[2], mm[3]));  // lane-local max
      if (!__all(mt - m_run[nf] <= 8.0f)) {   // rare: true reduce + rescale
        mt = fmaxf(mt, __shfl_xor(mt, 16));
        mt = fmaxf(mt, __shfl_xor(mt, 32));
        float mn = fmaxf(m_run[nf], mt);
        float al = exp2_fast(m_run[nf] - mn);
        m_run[nf] = mn;
        l_acc[nf] *= al;
#pragma unroll
        for (int mfd = 0; mfd < 4; ++mfd) o_[mfd][nf] *= al;
      }
      float mn = m_run[nf];                   // p = 2^(s-mn) <= 2^8
#pragma unroll
      for (int mf = 0; mf < 4; ++mf)
#pragma unroll
        for (int r = 0; r < 4; ++r) s[mf][nf][r] = exp2_fast(s[mf][nf][r] - mn);
      l_acc[nf] += (s[0][nf] + s[1][nf]) + (s[2][nf] + s[3][nf]);
    }

    // PV: O^T += V^T * P^T.  P slot k-map equals C-frag row map (lane-local);
    // V^T A-frags read with the SAME slot map -> consistent contraction.
#pragma unroll
    for (int kap = 0; kap < 2; ++kap) {
      u16x8 pb[2];
#pragma unroll
      for (int nf = 0; nf < 2; ++nf) {
        uint4 wd;
        wd.x = cvt_pk_bf16(s[2 * kap][nf][0],     s[2 * kap][nf][1]);
        wd.y = cvt_pk_bf16(s[2 * kap][nf][2],     s[2 * kap][nf][3]);
        wd.z = cvt_pk_bf16(s[2 * kap + 1][nf][0], s[2 * kap + 1][nf][1]);
        wd.w = cvt_pk_bf16(s[2 * kap + 1][nf][2], s[2 * kap + 1][nf][3]);
        pb[nf] = __builtin_bit_cast(u16x8, wd);
      }
#pragma unroll
      for (int mfd = 0; mfd < 4; ++mfd) {
        int e = (c + 16 * mfd) * 128 + kap * 64 + g * 8;   // bytes in V^T tile
        u16x4 lo = *(const u16x4*)(vb + swz7(e));
        u16x4 hi = *(const u16x4*)(vb + swz7(e + 32));
        u16x8 vf = __builtin_shufflevector(lo, hi, 0, 1, 2, 3, 4, 5, 6, 7);
        o_[mfd][0] = mfma16(vf, pb[0], o_[mfd][0]);
        o_[mfd][1] = mfma16(vf, pb[1], o_[mfd][1]);
      }
    }
  };

  for (int tp = 0; tp < 32; ++tp) {
    const int bi = (tp & 1) * 2;               // buffers bi, bi+1 hold tiles 2tp, 2tp+1
    uint4 rgK[2][2], rgV[2][2];
    if (tp < 31) {                              // issue prefetch for tiles 2tp+2, 2tp+3
#pragma unroll
      for (int u = 0; u < 2; ++u) {
        const int kv1 = (2 * tp + 2 + u) * 64;
#pragma unroll
        for (int it = 0; it < 2; ++it) {
          int r = it * 32 + rr;
          rgK[u][it] = *(const uint4*)(gK + (kv1 + r) * 64 + co * 8);
          rgV[u][it] = *(const uint4*)(gV + r * 4096 + kv1 + co * 8);
        }
      }
    }
    tile_step((const char*)Ks + bi * 8192,       (const char*)Vs + bi * 8192);
    tile_step((const char*)Ks + (bi + 1) * 8192, (const char*)Vs + (bi + 1) * 8192);
    if (tp < 31) {                              // write-late into the other pair
#pragma unroll
      for (int u = 0; u < 2; ++u) {
        char* kd = (char*)Ks + ((bi ^ 2) + u) * 8192;
        char* vd = (char*)Vs + ((bi ^ 2) + u) * 8192;
#pragma unroll
        for (int it = 0; it < 2; ++it) {
          int r  = it * 32 + rr;
          int by = swz7(r * 128 + co * 16);
          *(uint4*)(kd + by) = rgK[u][it];
          *(uint4*)(vd + by) = rgV[u][it];
        }
      }
    }
    __syncthreads();                            // one barrier per 2 tiles
  }

  // epilogue: reduce per-lane l partials once, store bf16 attn
#pragma unroll
  for (int nf = 0; nf < 2; ++nf) {
    float l = (l_acc[nf][0] + l_acc[nf][1]) + (l_acc[nf][2] + l_acc[nf][3]);
    l += __shfl_xor(l, 16);
    l += __shfl_xor(l, 32);
    float inv = 1.0f / l;
    int q = q0 + w * 32 + nf * 16 + c;
#pragma unroll
    for (int mfd = 0; mfd < 4; ++mfd) {
      u16x4 pk;
#pragma unroll
      for (int r = 0; r < 4; ++r) pk[r] = f2bf(o_[mfd][nf][r] * inv);
      *(u16x4*)&ab[q * 512 + h * 64 + mfd * 16 + 4 * g] = pk;
    }
  }
}

// ------------------------------------------------------------- gemm_out
// 64x128 tile, 512 threads = 8 waves (4m x 2n), wave tile 16x64.
__global__ __launch_bounds__(512) void gemm_out(
    const u16* __restrict__ ab, const u16* __restrict__ wob,
    const float* __restrict__ bo, float* __restrict__ out)
{
  __shared__ __align__(16) u16 As[2 * 64 * 64];    // 16KB
  __shared__ __align__(16) u16 Bs[2 * 128 * 64];   // 32KB
  const int tid = threadIdx.x, bm = blockIdx.x, bn = blockIdx.y;
  const int lane = tid & 63, wid = tid >> 6;
  const int wm = wid >> 1, wn = wid & 1;
  const int c = lane & 15, g = lane >> 4;
  const int rr = tid >> 3, co = tid & 7;
  const f32x4 Z4 = {0.f, 0.f, 0.f, 0.f};
  f32x4 acc[4];
#pragma unroll
  for (int b = 0; b < 4; ++b) acc[b] = Z4;
  const u16* Ab = ab  + (bm * 64 + rr) * 512 + co * 8;     // rr 0..63
  const u16* Wb = wob + (bn * 128 + rr) * 512 + co * 8;
  *(uint4*)((char*)As + swz7(rr * 128 + co * 16)) = *(const uint4*)(Ab);
#pragma unroll
  for (int it = 0; it < 2; ++it)
    *(uint4*)((char*)Bs + swz7((it * 64 + rr) * 128 + co * 16)) =
        *(const uint4*)(Wb + it * 64 * 512);
  __syncthreads();
  for (int kt = 0; kt < 8; ++kt) {
    const int cur = kt & 1;
    uint4 pa, pw[2];
    if (kt < 7) {
      pa = *(const uint4*)(Ab + (kt + 1) * 64);
#pragma unroll
      for (int it = 0; it < 2; ++it)
        pw[it] = *(const uint4*)(Wb + it * 64 * 512 + (kt + 1) * 64);
    }
    const char* Ar = (const char*)As + cur * 8192;
    const char* Wr = (const char*)Bs + cur * 16384;
#pragma unroll
    for (int kk = 0; kk < 2; ++kk) {
      u16x8 af, bfr[4];
      af = *(const u16x8*)(Ar + swz7((wm * 16 + c) * 128 + kk * 64 + g * 16));
#pragma unroll
      for (int nf = 0; nf < 4; ++nf) {
        int row = wn * 64 + nf * 16 + c;
        bfr[nf] = *(const u16x8*)(Wr + swz7(row * 128 + kk * 64 + g * 16));
      }
#pragma unroll
      for (int nf = 0; nf < 4; ++nf)
        acc[nf] = mfma16(af, bfr[nf], acc[nf]);
    }
    if (kt < 7) {
      char* Ad = (char*)As + (cur ^ 1) * 8192;
      char* Wd = (char*)Bs + (cur ^ 1) * 16384;
      *(uint4*)(Ad + swz7(rr * 128 + co * 16)) = pa;
#pragma unroll
      for (int it = 0; it < 2; ++it)
        *(uint4*)(Wd + swz7((it * 64 + rr) * 128 + co * 16)) = pw[it];
    }
    __syncthreads();
  }
#pragma unroll
  for (int nf = 0; nf < 4; ++nf) {
    int o  = bn * 128 + wn * 64 + nf * 16 + c;
    int ib = bm * 64 + wm * 16 + 4 * g;
    float bb = bo[o];
#pragma unroll
    for (int r = 0; r < 4; ++r) out[(ib + r) * 512 + o] = acc[nf][r] + bb;
  }
}

// ------------------------------------------------------------- launch
extern "C" void kernel_launch(void* const* d_in, const int* in_sizes, int n_in,
                              void* d_out, int out_size, void* d_ws, size_t ws_size,
                              hipStream_t stream) {
  (void)in_sizes; (void)n_in; (void)out_size; (void)ws_size;
  const float* x  = (const float*)d_in[0];
  const float* Wq = (const float*)d_in[1];
  const float* bq = (const float*)d_in[2];
  const float* Wk = (const float*)d_in[3];
  const float* bk = (const float*)d_in[4];
  const float* Wv = (const float*)d_in[5];
  const float* bv = (const float*)d_in[6];
  const float* Wo = (const float*)d_in[7];
  const float* bo = (const float*)d_in[8];
  char* ws = (char*)d_ws;
  u16* xb  = (u16*)(ws + 0);           // x bf16            4 MB
  u16* wqb = (u16*)(ws + 4194304);     // weights bf16  4x 0.5 MB
  u16* wkb = (u16*)(ws + 4718592);
  u16* wvb = (u16*)(ws + 5242880);
  u16* wob = (u16*)(ws + 5767168);
  u16* Qw  = (u16*)(ws + 6291456);     // Q  [8][4096][64]  4 MB (scaled)
  u16* Kw  = (u16*)(ws + 10485760);    // K  [8][4096][64]  4 MB
  u16* Vt  = (u16*)(ws + 14680064);    // V^T [8][64][4096] 4 MB
  u16* ab  = (u16*)(ws + 18874368);    // attn bf16 [4096][512] 4 MB

  conv_all<<<3072, 256, 0, stream>>>(x, Wq, Wk, Wv, Wo, xb, wqb, wkb, wvb, wob);
  gemm_qkv<<<dim3(32, 4, 3), 512, 0, stream>>>(xb, wqb, wkb, wvb, bq, bk, bv, Qw, Kw, Vt);
  attn_fwd<<<256, 256, 0, stream>>>(Qw, Kw, Vt, ab);
  gemm_out<<<dim3(64, 4), 512, 0, stream>>>(ab, wob, bo, (float*)d_out);
}